// Round 1
// baseline (756.296 us; speedup 1.0000x reference)
//
#include <hip/hip_runtime.h>
#include <hip/hip_bf16.h>
#include <cstdint>

#define T_TOKENS 4096
#define DMODEL   1024
#define DHIDDEN  4096
#define NEXP     8
#define GB       256      // gemm blocks: 1/CU at 128 KB LDS
#define TSTRIDE  128      // per-XCD task-list stride

typedef __bf16 bf16x8 __attribute__((ext_vector_type(8)));
typedef float  f32x4  __attribute__((ext_vector_type(4)));
typedef unsigned short ushort_t;

// ---------- helpers ----------

__device__ __forceinline__ ushort_t f2bf(float f) {
  union { float f; uint32_t u; } c; c.f = f;
  uint32_t r = c.u + 0x7fffu + ((c.u >> 16) & 1u);   // RNE
  return (ushort_t)(r >> 16);
}

__device__ __forceinline__ void gload_lds16(const void* g, void* l) {
  __builtin_amdgcn_global_load_lds(
      (const __attribute__((address_space(1))) unsigned int*)g,
      (__attribute__((address_space(3))) unsigned int*)l, 16, 0, 0);
}

__device__ __forceinline__ float wave_sum(float v) {
  #pragma unroll
  for (int m = 32; m; m >>= 1) v += __shfl_xor(v, m, 64);
  return v;
}

// ---------- 1. weight convert + transpose: W [E][M][N] f32 -> WT [E][N][M] bf16 ----------

template <int M, int N>
__global__ __launch_bounds__(256)
void convertT_kernel(const float* __restrict__ W, ushort_t* __restrict__ WT) {
  __shared__ float tile[64][65];
  int e  = blockIdx.z;
  int c0 = blockIdx.x * 64;          // N dim
  int r0 = blockIdx.y * 64;          // M dim
  const float* Wp = W + (size_t)e * M * N;
  ushort_t*    Tp = WT + (size_t)e * M * N;
  int t  = threadIdx.x;
  int lr = t >> 4;                   // 0..15
  int lc = (t & 15) * 4;
  #pragma unroll
  for (int i = 0; i < 4; ++i) {
    float4 v = *(const float4*)&Wp[(size_t)(r0 + lr + 16 * i) * N + c0 + lc];
    *(float4*)&tile[lr + 16 * i][lc] = v;
  }
  __syncthreads();
  int sn = t >> 4;                   // n within tile (0..15, +16i)
  int sm = (t & 15) * 4;             // m within tile
  #pragma unroll
  for (int i = 0; i < 4; ++i) {
    int n = sn + 16 * i;
    ushort_t o4[4];
    #pragma unroll
    for (int j = 0; j < 4; ++j) o4[j] = f2bf(tile[sm + j][n]);
    *(uint64_t*)&Tp[(size_t)(c0 + n) * M + r0 + sm] = *(uint64_t*)o4;
  }
}

// ---------- 2. gating: fp32 logits, top-2, softmax, counts ----------

__global__ void gating_kernel(const float* __restrict__ x, const float* __restrict__ Wg,
                              const float* __restrict__ bg, float* __restrict__ logits_out,
                              int* __restrict__ meta, int* __restrict__ ek,
                              float* __restrict__ wk) {
  __shared__ float sWg[DMODEL * NEXP];               // 32 KB
  int tid = threadIdx.x;
  for (int i = tid; i < DMODEL * NEXP; i += 256) sWg[i] = Wg[i];
  __syncthreads();
  int wave = tid >> 6, lane = tid & 63;
  int t = blockIdx.x * 4 + wave;
  const float* xr = x + (size_t)t * DMODEL;
  float a0 = 0, a1 = 0, a2 = 0, a3 = 0, a4 = 0, a5 = 0, a6 = 0, a7 = 0;
  for (int d = lane; d < DMODEL; d += 64) {
    float xv = xr[d];
    const float4* w4 = (const float4*)&sWg[d * 8];
    float4 wa = w4[0], wb = w4[1];
    a0 += xv * wa.x; a1 += xv * wa.y; a2 += xv * wa.z; a3 += xv * wa.w;
    a4 += xv * wb.x; a5 += xv * wb.y; a6 += xv * wb.z; a7 += xv * wb.w;
  }
  a0 = wave_sum(a0); a1 = wave_sum(a1); a2 = wave_sum(a2); a3 = wave_sum(a3);
  a4 = wave_sum(a4); a5 = wave_sum(a5); a6 = wave_sum(a6); a7 = wave_sum(a7);
  if (lane == 0) {
    float lg[NEXP] = {a0 + bg[0], a1 + bg[1], a2 + bg[2], a3 + bg[3],
                      a4 + bg[4], a5 + bg[5], a6 + bg[6], a7 + bg[7]};
    #pragma unroll
    for (int e = 0; e < NEXP; ++e) logits_out[(size_t)t * NEXP + e] = lg[e];
    int i0 = 0; float v0 = lg[0];
    #pragma unroll
    for (int e = 1; e < NEXP; ++e) if (lg[e] > v0) { v0 = lg[e]; i0 = e; }
    int i1 = -1; float v1 = -3.4e38f;
    #pragma unroll
    for (int e = 0; e < NEXP; ++e) if (e != i0 && lg[e] > v1) { v1 = lg[e]; i1 = e; }
    float ex = expf(v1 - v0);
    float w0 = 1.f / (1.f + ex);
    float w1 = ex / (1.f + ex);
    ek[t * 2]     = i0;  ek[t * 2 + 1] = i1;
    wk[t * 2]     = w0;  wk[t * 2 + 1] = w1;
    atomicAdd(&meta[i0], 1);
    atomicAdd(&meta[i1], 1);
  }
}

// ---------- 3. prefix offsets + per-XCD task lists (256x256 tiles) ----------
// meta: [0:8) counts, [8:16) offs, [16:24) scatter cursors,
// [24] GEMM1 per-XCD task count (= 2*p), [25] GEMM2 total task count (= 12*p).
// Task = (e<<13)|(kh<<11)|(rt<<5)|ct.
// GEMM1: tiles (e, rt, ct in [0,16)); XCD x owns ct in {x, x+8}; order (e, ct, rt).
// GEMM2: tiles (e, kh in [0,3), rt, ct in [0,4)); flattened round-robin over XCDs.

__global__ void offsets_kernel(int* __restrict__ meta, int* __restrict__ tasks1,
                               int* __restrict__ tasks2) {
  __shared__ int snrt[NEXP], spsum[NEXP + 1];
  int tid = threadIdx.x;
  if (tid == 0) {
    int s = 0, p = 0;
    for (int e = 0; e < NEXP; ++e) {
      meta[8 + e] = s;
      int cnt = meta[e];
      s += cnt;
      int n = (cnt + 255) >> 8;
      snrt[e] = n;
      spsum[e] = p; p += n;
    }
    spsum[NEXP] = p;
    meta[24] = 2 * p;                 // tasks per XCD, GEMM1
    meta[25] = 12 * p;                // total tasks, GEMM2
  }
  __syncthreads();
  if (tid < 128) {                    // GEMM1: (x, e, cti)
    int x = tid >> 4, e = (tid >> 1) & 7, cti = tid & 1;
    int n = snrt[e];
    int ct = cti * 8 + x;
    int base = x * TSTRIDE + 2 * spsum[e] + cti * n;
    for (int r = 0; r < n; ++r) tasks1[base + r] = (e << 13) | (r << 5) | ct;
  }
  if (tid < 96) {                     // GEMM2: (e, kh, ct)
    int e = tid / 12, rem = tid % 12, kh = rem >> 2, ct = rem & 3;
    int n = snrt[e];
    int fbase = 12 * spsum[e] + (kh * 4 + ct) * n;
    for (int r = 0; r < n; ++r) {
      int f = fbase + r;
      tasks2[(f & 7) * TSTRIDE + (f >> 3)] = (e << 13) | (kh << 11) | (r << 5) | ct;
    }
  }
}

// ---------- 4. scatter/gather: x rows -> bf16 Xg in expert-segment order ----------

__global__ void scatter_kernel(const float* __restrict__ x, const int* __restrict__ ek,
                               int* __restrict__ meta, int* __restrict__ inv,
                               ushort_t* __restrict__ Xg) {
  int b = blockIdx.x;                // 0..2T-1
  int t = b >> 1, k = b & 1;
  __shared__ int spos;
  if (threadIdx.x == 0) {
    int e   = ek[t * 2 + k];
    int pos = meta[8 + e] + atomicAdd(&meta[16 + e], 1);
    inv[t * 2 + k] = pos;
    spos = pos;
  }
  __syncthreads();
  int pos = spos;
  float4 v = ((const float4*)(x + (size_t)t * DMODEL))[threadIdx.x];
  ushort_t* dst = Xg + (size_t)pos * DMODEL + threadIdx.x * 4;
  dst[0] = f2bf(v.x); dst[1] = f2bf(v.y); dst[2] = f2bf(v.z); dst[3] = f2bf(v.w);
}

// ---------- 5. grouped GEMM, 256x256 tile, 8-wave, 8-phase counted-vmcnt pipeline ----
// Per K-tile (BK=64): 4 phases. Phase q reads A rows [64q,64q+64) (sweep) so the
// same-buffer prefetch of tile t+2 is write-safe one phase after last reader:
//   q0: stage A1(t+1) -> buf^1 ; q1: B1(t+2) -> buf ; q2: B0(t+2) ; q3: A0(t+2)
// vmcnt(6) once per tile (3 half-tiles = 6 loads in flight); vmcnt(0) at tail.
// LDS XOR swizzle: stored block = blk ^ (row&7), pre-swizzled on the global source
// (gload_lds dest must stay linear), applied again on ds_read.

template <int KTOT, int NTOT, bool FUSE>
__global__ __launch_bounds__(512, 2)
void moe_gemm256(const ushort_t* __restrict__ A, const ushort_t* __restrict__ BT,
                 const int* __restrict__ meta, const int* __restrict__ tasks,
                 const float* __restrict__ bias, ushort_t* __restrict__ outb,
                 float* __restrict__ y0, float* __restrict__ y1,
                 float* __restrict__ y2) {
  int x    = blockIdx.x & 7;
  int slot = blockIdx.x >> 3;
  int nloc;
  if (FUSE) nloc = meta[24];
  else { int W2 = meta[25]; nloc = (W2 >> 3) + ((x < (W2 & 7)) ? 1 : 0); }
  const int* myTasks = tasks + x * TSTRIDE;

  __shared__ __align__(16) ushort_t lds[2 * 2 * 256 * 64];   // 128 KB

  int tid  = threadIdx.x;
  int wave = tid >> 6, lane = tid & 63;
  int wr = wave >> 2, wc = wave & 3;           // 2 x 4 wave grid
  int quad = lane >> 4, m16 = lane & 15;
  int sr = lane >> 3;                          // staging row-within-8
  int sb = (lane & 7) ^ sr;                    // staging source block (pre-swizzled)
  int swk0 = quad ^ (m16 & 7);                 // read swizzle, kk=0
  int swk1 = (4 + quad) ^ (m16 & 7);           // read swizzle, kk=1
  int aRow = wr * 16 + m16;
  int bRow = wc * 16 + m16;

  for (int ti = slot; ti < nloc; ti += GB / 8) {
    int task = myTasks[ti];
    int e  = task >> 13;
    int kh = (task >> 11) & 3;
    int rt = (task >> 5) & 63;
    int ct = task & 31;
    int cnt     = meta[e];
    int rowBase = meta[8 + e] + rt * 256;
    int n0      = ct * 256;
    int kb, NT;
    if (FUSE) { kb = 0; NT = KTOT / 64; }
    else      { kb = (kh == 0) ? 0 : 21 * kh + 1; NT = (kh == 0) ? 22 : 21; }

    const ushort_t* Ag = A + (size_t)rowBase * KTOT;
    const ushort_t* Bg = BT + (size_t)e * NTOT * KTOT + (size_t)n0 * KTOT;

    // one 128x64 half-tile: 2 gload_lds / thread, linear LDS dest
    auto stage = [&](const ushort_t* gbase, int h, int t_, int mat) {
      ushort_t* lb = lds + ((size_t)((t_ & 1) * 2 + mat)) * 16384 + h * 8192;
      const ushort_t* gb = gbase + (size_t)(h * 128) * KTOT + (kb + t_) * 64;
      #pragma unroll
      for (int rd = 0; rd < 2; ++rd) {
        int row = rd * 64 + wave * 8 + sr;
        gload_lds16(gb + (size_t)row * KTOT + sb * 8,
                    lb + rd * 4096 + wave * 512);
      }
    };

    // prologue: tile0 complete + 3 half-tiles of tile1
    stage(Ag, 0, 0, 0); stage(Ag, 1, 0, 0);
    stage(Bg, 0, 0, 1); stage(Bg, 1, 0, 1);
    if (NT > 1) { stage(Ag, 0, 1, 0); stage(Bg, 0, 1, 1); stage(Bg, 1, 1, 1); }

    f32x4 acc[8][4];
    #pragma unroll
    for (int i = 0; i < 8; ++i)
      #pragma unroll
      for (int j = 0; j < 4; ++j) acc[i][j] = (f32x4){0.f, 0.f, 0.f, 0.f};

    if (NT > 1) asm volatile("s_waitcnt vmcnt(6)" ::: "memory");
    else        asm volatile("s_waitcnt vmcnt(0)" ::: "memory");
    __builtin_amdgcn_s_barrier();

    for (int t = 0; t < NT; ++t) {
      const ushort_t* lA = lds + ((size_t)((t & 1) * 2)) * 16384;
      const ushort_t* lB = lA + 16384;
      bf16x8 bfr[4][2];
      #pragma unroll
      for (int q = 0; q < 4; ++q) {
        bf16x8 af[2][2];
        #pragma unroll
        for (int ii = 0; ii < 2; ++ii) {
          int row = (q * 2 + ii) * 32 + aRow;
          af[ii][0] = *(const bf16x8*)&lA[row * 64 + swk0 * 8];
          af[ii][1] = *(const bf16x8*)&lA[row * 64 + swk1 * 8];
        }
        if (q == 0) {
          #pragma unroll
          for (int j = 0; j < 4; ++j) {
            int row = j * 64 + bRow;
            bfr[j][0] = *(const bf16x8*)&lB[row * 64 + swk0 * 8];
            bfr[j][1] = *(const bf16x8*)&lB[row * 64 + swk1 * 8];
          }
        }
        if (q == 0 && t + 1 < NT) stage(Ag, 1, t + 1, 0);
        if (q == 1 && t + 2 < NT) stage(Bg, 1, t + 2, 1);
        if (q == 2 && t + 2 < NT) stage(Bg, 0, t + 2, 1);
        if (q == 3 && t + 2 < NT) stage(Ag, 0, t + 2, 0);
        __builtin_amdgcn_s_barrier();
        asm volatile("s_waitcnt lgkmcnt(0)" ::: "memory");
        __builtin_amdgcn_sched_barrier(0);
        __builtin_amdgcn_s_setprio(1);
        #pragma unroll
        for (int ii = 0; ii < 2; ++ii)
          #pragma unroll
          for (int j = 0; j < 4; ++j) {
            acc[q * 2 + ii][j] = __builtin_amdgcn_mfma_f32_16x16x32_bf16(
                af[ii][0], bfr[j][0], acc[q * 2 + ii][j], 0, 0, 0);
            acc[q * 2 + ii][j] = __builtin_amdgcn_mfma_f32_16x16x32_bf16(
                af[ii][1], bfr[j][1], acc[q * 2 + ii][j], 0, 0, 0);
          }
        __builtin_amdgcn_s_setprio(0);
        if (q == 3) {
          if (t + 2 < NT) asm volatile("s_waitcnt vmcnt(6)" ::: "memory");
          else            asm volatile("s_waitcnt vmcnt(0)" ::: "memory");
        }
        __builtin_amdgcn_s_barrier();
      }
    }

    // epilogue: D row = quad*4 + reg, col = m16 within each 16x16 fragment
    float* yo = FUSE ? nullptr : (kh == 0 ? y0 : (kh == 1 ? y1 : y2));
    #pragma unroll
    for (int i = 0; i < 8; ++i) {
      int rBase = i * 32 + wr * 16 + quad * 4;
      #pragma unroll
      for (int j = 0; j < 4; ++j) {
        int col = n0 + j * 64 + wc * 16 + m16;
        #pragma unroll
        for (int r = 0; r < 4; ++r) {
          int rowIn = rBase + r;
          if (rt * 256 + rowIn < cnt) {
            size_t grow = (size_t)(rowBase + rowIn);
            float v = acc[i][j][r];
            if (FUSE) {
              v += bias[e * NTOT + col];
              v = fmaxf(v, 0.f);
              outb[grow * NTOT + col] = f2bf(v);
            } else {
              yo[grow * NTOT + col] = v;
            }
          }
        }
      }
    }
  }
}

// ---------- 6. combine: out[t] = sum_k wk*(y0[pk]+y1[pk]+y2[pk]+b2[ek]) ----------

__global__ void combine_kernel(const float* __restrict__ yA, const float* __restrict__ yB,
                               const float* __restrict__ yC, const int* __restrict__ inv,
                               const int* __restrict__ ek, const float* __restrict__ wk,
                               const float* __restrict__ b2, float* __restrict__ out) {
  int t = blockIdx.x;
  int d = threadIdx.x * 4;
  int p0 = inv[t * 2], p1 = inv[t * 2 + 1];
  int e0 = ek[t * 2],  e1 = ek[t * 2 + 1];
  float w0 = wk[t * 2], w1 = wk[t * 2 + 1];
  float4 a0 = *(const float4*)&yA[(size_t)p0 * DMODEL + d];
  float4 b0 = *(const float4*)&yB[(size_t)p0 * DMODEL + d];
  float4 c0 = *(const float4*)&yC[(size_t)p0 * DMODEL + d];
  float4 a1 = *(const float4*)&yA[(size_t)p1 * DMODEL + d];
  float4 b1 = *(const float4*)&yB[(size_t)p1 * DMODEL + d];
  float4 c1 = *(const float4*)&yC[(size_t)p1 * DMODEL + d];
  float4 q0 = *(const float4*)&b2[(size_t)e0 * DMODEL + d];
  float4 q1 = *(const float4*)&b2[(size_t)e1 * DMODEL + d];
  float4 o;
  o.x = w0 * (a0.x + b0.x + c0.x + q0.x) + w1 * (a1.x + b1.x + c1.x + q1.x);
  o.y = w0 * (a0.y + b0.y + c0.y + q0.y) + w1 * (a1.y + b1.y + c1.y + q1.y);
  o.z = w0 * (a0.z + b0.z + c0.z + q0.z) + w1 * (a1.z + b1.z + c1.z + q1.z);
  o.w = w0 * (a0.w + b0.w + c0.w + q0.w) + w1 * (a1.w + b1.w + c1.w + q1.w);
  *(float4*)&out[(size_t)t * DMODEL + d] = o;
}

// ---------- launch ----------

extern "C" void kernel_launch(void* const* d_in, const int* in_sizes, int n_in,
                              void* d_out, int out_size, void* d_ws, size_t ws_size,
                              hipStream_t stream) {
  const float* x  = (const float*)d_in[0];
  const float* Wg = (const float*)d_in[1];
  const float* bg = (const float*)d_in[2];
  const float* W1 = (const float*)d_in[3];
  const float* b1 = (const float*)d_in[4];
  const float* W2 = (const float*)d_in[5];
  const float* b2 = (const float*)d_in[6];
  float* out    = (float*)d_out;
  float* logits = out + (size_t)T_TOKENS * DMODEL;

  char* ws = (char*)d_ws;
  size_t off = 0;
  auto alloc = [&](size_t b) { size_t r = off; off += (b + 255) & ~(size_t)255; return r; };
  ushort_t* W1T  = (ushort_t*)(ws + alloc((size_t)NEXP * DMODEL * DHIDDEN * 2)); // 67.1 MB
  ushort_t* W2T  = (ushort_t*)(ws + alloc((size_t)NEXP * DMODEL * DHIDDEN * 2)); // 67.1 MB
  ushort_t* Xg   = (ushort_t*)(ws + alloc((size_t)(2 * T_TOKENS + 256) * DMODEL * 2));   // 17.3 MB
  ushort_t* hbuf = (ushort_t*)(ws + alloc((size_t)(2 * T_TOKENS + 256) * DHIDDEN * 2));  // 69.2 MB
  float*    ybuf = (float*)(ws + alloc((size_t)2 * T_TOKENS * DMODEL * 4));              // 33.6 MB
  int*      meta = (int*)(ws + alloc(4096));
  int*      ek   = (int*)(ws + alloc((size_t)T_TOKENS * 2 * 4));
  float*    wk   = (float*)(ws + alloc((size_t)T_TOKENS * 2 * 4));
  int*      inv  = (int*)(ws + alloc((size_t)T_TOKENS * 2 * 4));
  int*      tk1  = (int*)(ws + alloc(8 * TSTRIDE * 4));
  int*      tk2  = (int*)(ws + alloc(8 * TSTRIDE * 4));
  // GEMM2 K-split partials 1,2 alias W1T (dead after GEMM1): 2 x 33.55 MB = 67.1 MB exact
  float* yp1 = (float*)W1T;
  float* yp2 = yp1 + (size_t)2 * T_TOKENS * DMODEL;
  (void)ws_size; (void)in_sizes; (void)n_in; (void)out_size;

  hipMemsetAsync(meta, 0, 256, stream);

  convertT_kernel<DMODEL, DHIDDEN>
      <<<dim3(DHIDDEN / 64, DMODEL / 64, NEXP), 256, 0, stream>>>(W1, W1T);
  convertT_kernel<DHIDDEN, DMODEL>
      <<<dim3(DMODEL / 64, DHIDDEN / 64, NEXP), 256, 0, stream>>>(W2, W2T);

  gating_kernel<<<T_TOKENS / 4, 256, 0, stream>>>(x, Wg, bg, logits, meta, ek, wk);
  offsets_kernel<<<1, 256, 0, stream>>>(meta, tk1, tk2);
  scatter_kernel<<<T_TOKENS * 2, 256, 0, stream>>>(x, ek, meta, inv, Xg);

  moe_gemm256<DMODEL, DHIDDEN, true>
      <<<GB, 512, 0, stream>>>(Xg, W1T, meta, tk1, b1, hbuf, nullptr, nullptr, nullptr);
  moe_gemm256<DHIDDEN, DMODEL, false>
      <<<GB, 512, 0, stream>>>(hbuf, W2T, meta, tk2, nullptr, nullptr, ybuf, yp1, yp2);

  combine_kernel<<<T_TOKENS, 256, 0, stream>>>(ybuf, yp1, yp2, inv, ek, wk, b2, out);
}